// Round 3
// baseline (773.696 us; speedup 1.0000x reference)
//
#include <hip/hip_runtime.h>
#include <math.h>

// ---- problem constants ----
constexpr int B  = 32;
constexpr int N  = 196;   // tokens
constexpr int D  = 768;   // channels
constexpr int E  = 200;   // experts
constexpr int TK = 20;    // top-k
constexpr int H  = 196;   // hidden

constexpr int NP = 224;   // padded K-dim (196 -> 7*32)
constexpr int LK = 40;    // LDS stride for k_outproj tiles

constexpr int NGRP = 4;   // expert groups (5 experts each)
// W tile format: per expert, per matrix: 7 chunks x [k4 0..3][row 0..223] x 16B
// chunk bytes = 4*224*16 = 14336; expert bytes = 7*14336 = 100352
constexpr int CHB = 14336;
constexpr int EXB = 100352;

typedef __bf16 bf16x8 __attribute__((ext_vector_type(8)));
typedef __bf16 bf16x4 __attribute__((ext_vector_type(4)));
typedef float  f32x4  __attribute__((ext_vector_type(4)));

#define GLDS16(gp, lp)                                                        \
  __builtin_amdgcn_global_load_lds(                                           \
      (const __attribute__((address_space(1))) void*)(gp),                    \
      (__attribute__((address_space(3))) void*)(lp), 16, 0, 0)

// s_waitcnt immediates (gfx9 encoding: vm[3:0]|exp[6:4]|lgkm[11:8]|vm[15:14])
#define WAITVM2   __builtin_amdgcn_s_waitcnt(0x0F72)  // vmcnt<=2, ignore exp/lgkm
#define WAITLGKM0 __builtin_amdgcn_s_waitcnt(0xC07F)  // lgkmcnt==0, ignore vm/exp
#define BAR       __builtin_amdgcn_s_barrier()

// fast tanh-gelu: x * sigmoid(1.595769*(x + 0.044715 x^3)); exp2 form.
__device__ __forceinline__ float gelu_fast(float x) {
  float u = x * fmaf(x * x, 0.044715f, 1.0f);
  float e = exp2f(-2.3022084f * u);   // 1.595769 * log2(e)
  return x * __builtin_amdgcn_rcpf(1.0f + e);
}

// ---------------------------------------------------------------------------
// Kernel 1: fused token-mean + layernorm-over-N, write z bf16 (B,D,224) padded
// ---------------------------------------------------------------------------
__global__ void k_ln(const float* __restrict__ x, __bf16* __restrict__ zb,
                     float* __restrict__ mu) {
  int t = blockIdx.x * 256 + threadIdx.x;        // [0, B*D)
  if (t >= B * D) return;
  int b = t / D;
  const float* xp = x + (size_t)b * N * D + (t % D);
  float s = 0.f, sq = 0.f;
  #pragma unroll 4
  for (int n = 0; n < N; ++n) {
    float v = xp[(size_t)n * D];
    s += v; sq += v * v;
  }
  float m   = s * (1.0f / N);
  float var = sq * (1.0f / N) - m * m;
  float rs  = rsqrtf(var + 1e-5f);
  mu[t] = m;
  __bf16* zr = zb + (size_t)t * NP;
  #pragma unroll 4
  for (int n = 0; n < N; ++n) {
    float v = xp[(size_t)n * D];
    zr[n] = (__bf16)((v - m) * rs);
  }
  for (int n = N; n < NP; ++n) zr[n] = (__bf16)0.f;
}

// ---------------------------------------------------------------------------
// Kernel 2a: W1,W2 -> transposed/tiled bf16 in the exact LDS staging format:
// dst[e][c][k4][row] 16B slots (row<196,k<196 data, else 0). grid (7,E,2).
// ---------------------------------------------------------------------------
__global__ void k_convert_t(const float* __restrict__ W1, const float* __restrict__ W2,
                            __bf16* __restrict__ W1t, __bf16* __restrict__ W2t) {
  int c = blockIdx.x;
  int e = blockIdx.y;
  const float* src = (blockIdx.z ? W2 : W1) + (size_t)e * 196 * 196;
  __bf16* dst = (blockIdx.z ? W2t : W1t);
  dst += (size_t)e * (EXB / 2) + c * (CHB / 2);
  for (int s = threadIdx.x; s < 896; s += 256) {
    int k4 = s / 224, row = s - k4 * 224;
    int k = c * 32 + k4 * 8;
    bf16x8 o = {(__bf16)0.f, (__bf16)0.f, (__bf16)0.f, (__bf16)0.f,
                (__bf16)0.f, (__bf16)0.f, (__bf16)0.f, (__bf16)0.f};
    if (row < 196) {
      const float* sr = src + row * 196 + k;
      #pragma unroll
      for (int i = 0; i < 8; ++i)
        if (k + i < 196) o[i] = (__bf16)sr[i];
    }
    *(bf16x8*)&dst[s * 8] = o;
  }
}

// Kernel 2b: Wo -> bf16
__global__ void k_convert_wo(const float* __restrict__ Wo, __bf16* __restrict__ Wob) {
  int t = blockIdx.x * 256 + threadIdx.x;        // [0, 147456)
  float4 v = *(const float4*)&Wo[t * 4];
  bf16x4 o = {(__bf16)v.x, (__bf16)v.y, (__bf16)v.z, (__bf16)v.w};
  *(bf16x4*)&Wob[t * 4] = o;
}

// ---------------------------------------------------------------------------
// Kernel 3: router — logits, softmax, top-20, renormalized weights.
// ---------------------------------------------------------------------------
__global__ void k_router(const float* __restrict__ mu, const float* __restrict__ Wr,
                         float* __restrict__ probs, int* __restrict__ idxg,
                         float* __restrict__ wg) {
  int b = blockIdx.x;
  int t = threadIdx.x;
  __shared__ float sp[E];
  __shared__ float smax, ssum;
  __shared__ float svals[TK];
  __shared__ int   sidx[TK];

  float logit = 0.f;
  if (t < E) {
    const float* m  = mu + (size_t)b * D;
    const float* wr = Wr + (size_t)t * D;
    float acc = 0.f;
    #pragma unroll 4
    for (int d = 0; d < D; ++d) acc = fmaf(m[d], wr[d], acc);
    logit = acc;
    sp[t] = acc;
  }
  __syncthreads();
  if (t == 0) {
    float mx = sp[0];
    for (int e = 1; e < E; ++e) mx = fmaxf(mx, sp[e]);
    smax = mx;
  }
  __syncthreads();
  if (t < E) sp[t] = expf(logit - smax);
  __syncthreads();
  if (t == 0) {
    float s = 0.f;
    for (int e = 0; e < E; ++e) s += sp[e];
    ssum = s;
  }
  __syncthreads();
  if (t < E) {
    sp[t] = sp[t] / ssum;
    probs[(size_t)b * E + t] = sp[t];
  }
  __syncthreads();

  for (int k = 0; k < TK; ++k) {
    if (t < 64) {
      float bv = -1e30f; int bi = 0;
      for (int e = t; e < E; e += 64) {
        float v = sp[e];
        if (v > bv) { bv = v; bi = e; }
      }
      #pragma unroll
      for (int off = 32; off > 0; off >>= 1) {
        float ov = __shfl_down(bv, off);
        int   oi = __shfl_down(bi, off);
        if (ov > bv || (ov == bv && oi < bi)) { bv = ov; bi = oi; }
      }
      if (t == 0) {
        svals[k] = bv; sidx[k] = bi;
        sp[bi] = -2e30f;
      }
    }
    __syncthreads();
  }
  if (t == 0) {
    float s = 0.f;
    for (int k = 0; k < TK; ++k) s += svals[k];
    float inv = 1.0f / s;
    for (int k = 0; k < TK; ++k) {
      wg[b * TK + k]   = svals[k] * inv;
      idxg[b * TK + k] = sidx[k];
    }
  }
}

// ---------------------------------------------------------------------------
// Kernel 4: aux loss -> out[B*N*D]
// ---------------------------------------------------------------------------
__global__ void k_aux(const float* __restrict__ probs, const int* __restrict__ idxg,
                      float* __restrict__ out_aux) {
  __shared__ float cs[E];
  int t = threadIdx.x;
  if (t < E) {
    float s = 0.f;
    for (int b = 0; b < B; ++b) s += probs[(size_t)b * E + t];
    cs[t] = s;
  }
  __syncthreads();
  if (t == 0) {
    float a = 0.f;
    for (int b = 0; b < B; ++b) a += cs[idxg[b * TK]];
    out_aux[0] = a * ((float)E / ((float)B * (float)B));
  }
}

// ---------------------------------------------------------------------------
// Kernel 5: fused expert MLP. 512 thr, 128-row d-tile, 1 block/CU (149KB LDS).
// Software-pipelined W staging: double-buffered chunks, raw s_barrier +
// manual s_waitcnt vmcnt(2) (chunk c+2 issued while computing chunk c+1).
// grid 768 = 8 XCD x 16 (b,g)-groups x 6 d-tiles, XCD-swizzled.
// ---------------------------------------------------------------------------
__global__ __launch_bounds__(512, 2) void k_expert(
    const __bf16* __restrict__ zb, const __bf16* __restrict__ W1t,
    const __bf16* __restrict__ W2t, const float* __restrict__ b1,
    const float* __restrict__ b2, const int* __restrict__ idxg,
    const float* __restrict__ wg, __bf16* __restrict__ mixp) {
  __shared__ alignas(16) __bf16 zs[28672];        // [k8 0..27][row 0..127] x 8
  __shared__ alignas(16) __bf16 at[28672];        // same layout
  __shared__ alignas(16) __bf16 ws[14336];        // 2 buffers x 7168 elems
  __shared__ float b1s[5 * 224];
  __shared__ float b2s[5 * 224];
  __shared__ int   eidx_s[8];
  __shared__ float w_s[8];

  int x = blockIdx.x & 7, rr_ = blockIdx.x >> 3;
  int j = rr_ / 6, dt = rr_ - j * 6;
  int gid = j * 8 + x;
  int g = gid & 3, b = gid >> 2;
  int d0 = dt * 128;

  int t = threadIdx.x;
  int lane = t & 63, wave = t >> 6;
  int quad = lane >> 4, l16 = lane & 15;
  int wrow = (wave & 3) * 32;
  int wcol = (wave >> 2) * 112;

  // ---- prologue: expert ids/weights + biases into LDS ----
  if (t < 5) {
    eidx_s[t] = idxg[b * TK + g * 5 + t];
    w_s[t]    = wg[b * TK + g * 5 + t];
  }
  for (int i = t; i < 1120; i += 512) {
    int kk = i / 224, col = i - kk * 224;
    int ee = idxg[b * TK + g * 5 + kk];
    b1s[i] = (col < 196) ? b1[ee * 196 + col] : 0.f;
    b2s[i] = (col < 196) ? b2[ee * 196 + col] : 0.f;
  }
  __syncthreads();

  // ---- z tile staging (transpose gather, one-time) ----
  {
    const char* zbase = (const char*)zb + (size_t)(b * D + d0) * (NP * 2);
    #pragma unroll
    for (int p = 0; p < 7; ++p) {
      int s = p * 512 + t;
      GLDS16(zbase + (s & 127) * (NP * 2) + (s >> 7) * 16, &zs[s * 8]);
    }
  }

  // ---- W staging offsets (flat contiguous chunk; duplicate slots for waves 6,7) ----
  int soff0 = t * 16;
  int soff1 = (t < 384) ? (512 + t) * 16 : (t - 384) * 16;

  auto issue = [&](int qn) {
    int qs = qn > 69 ? 69 : qn;
    int kq = qs / 14;
    int rem = qs - kq * 14;
    int ee = eidx_s[kq];
    const char* src;
    if (rem < 7) src = (const char*)W1t + (size_t)ee * EXB + rem * CHB;
    else         src = (const char*)W2t + (size_t)ee * EXB + (rem - 7) * CHB;
    char* lb = (char*)ws + (qn & 1) * CHB;
    GLDS16(src + soff0, lb + soff0);
    GLDS16(src + soff1, lb + soff1);
  };
  issue(0);
  issue(1);

  f32x4 macc[14];
  #pragma unroll
  for (int i = 0; i < 14; ++i) macc[i] = (f32x4){0.f, 0.f, 0.f, 0.f};

  int qn = 2;
  #pragma unroll 1
  for (int kk = 0; kk < 5; ++kk) {
    float wkv = w_s[kk];

    // ---- GEMM1: h = z @ W1^T ----
    f32x4 hacc[14];
    #pragma unroll
    for (int i = 0; i < 14; ++i) hacc[i] = (f32x4){0.f, 0.f, 0.f, 0.f};

    #pragma unroll 1
    for (int c = 0; c < 7; ++c) {
      WAITVM2;
      BAR;
      const __bf16* bp = ws + (c & 1) * 7168;
      bf16x8 a0 = *(const bf16x8*)&zs[(c * 4 + quad) * 1024 + (wrow + l16) * 8];
      bf16x8 a1 = *(const bf16x8*)&zs[(c * 4 + quad) * 1024 + (wrow + 16 + l16) * 8];
      #pragma unroll
      for (int ct = 0; ct < 7; ++ct) {
        bf16x8 bf = *(const bf16x8*)&bp[(quad * 224 + wcol + ct * 16 + l16) * 8];
        hacc[ct]     = __builtin_amdgcn_mfma_f32_16x16x32_bf16(a0, bf, hacc[ct], 0, 0, 0);
        hacc[7 + ct] = __builtin_amdgcn_mfma_f32_16x16x32_bf16(a1, bf, hacc[7 + ct], 0, 0, 0);
      }
      BAR;
      issue(qn); ++qn;
    }

    // ---- epilogue: a = gelu(h+b1)*w_k -> at ; macc += w_k*b2 ----
    #pragma unroll
    for (int ct = 0; ct < 7; ++ct) {
      int hcol = wcol + ct * 16 + l16;
      float bv  = b1s[kk * 224 + hcol];
      float b2v = b2s[kk * 224 + hcol] * wkv;
      #pragma unroll
      for (int rt = 0; rt < 2; ++rt) {
        f32x4 hv = hacc[rt * 7 + ct];
        #pragma unroll
        for (int rx = 0; rx < 4; ++rx) {
          int row = wrow + rt * 16 + quad * 4 + rx;
          float gv = gelu_fast(hv[rx] + bv) * wkv;
          at[((hcol >> 3) * 128 + row) * 8 + (hcol & 7)] = (__bf16)gv;
          macc[rt * 7 + ct][rx] += b2v;
        }
      }
    }
    WAITLGKM0;   // at-writes drained before the barrier in first GEMM2 chunk

    // ---- GEMM2: mix += a @ W2^T ----
    #pragma unroll 1
    for (int c = 0; c < 7; ++c) {
      WAITVM2;
      BAR;
      const __bf16* bp = ws + ((c + 1) & 1) * 7168;
      bf16x8 a0 = *(const bf16x8*)&at[(c * 4 + quad) * 1024 + (wrow + l16) * 8];
      bf16x8 a1 = *(const bf16x8*)&at[(c * 4 + quad) * 1024 + (wrow + 16 + l16) * 8];
      #pragma unroll
      for (int ct = 0; ct < 7; ++ct) {
        bf16x8 bf = *(const bf16x8*)&bp[(quad * 224 + wcol + ct * 16 + l16) * 8];
        macc[ct]     = __builtin_amdgcn_mfma_f32_16x16x32_bf16(a0, bf, macc[ct], 0, 0, 0);
        macc[7 + ct] = __builtin_amdgcn_mfma_f32_16x16x32_bf16(a1, bf, macc[7 + ct], 0, 0, 0);
      }
      BAR;
      issue(qn); ++qn;
    }
  }

  // ---- write partial mix (bf16): mixp[g][b][d][n] ----
  __bf16* mp = mixp + ((size_t)(g * B + b) * D + d0) * N;
  #pragma unroll
  for (int ct = 0; ct < 7; ++ct) {
    int ncol = wcol + ct * 16 + l16;
    if (ncol < N) {
      #pragma unroll
      for (int rt = 0; rt < 2; ++rt) {
        #pragma unroll
        for (int rx = 0; rx < 4; ++rx) {
          int dr = wrow + rt * 16 + quad * 4 + rx;
          mp[(size_t)dr * N + ncol] = (__bf16)macc[rt * 7 + ct][rx];
        }
      }
    }
  }
}

// ---------------------------------------------------------------------------
// Kernel 6: out = (sum_g mixp_g, as (B,N,D)) @ Wo^T + bo
// ---------------------------------------------------------------------------
__global__ __launch_bounds__(256, 2) void k_outproj(
    const __bf16* __restrict__ mixp, const __bf16* __restrict__ Wob,
    const float* __restrict__ bo, float* __restrict__ out) {
  __shared__ __bf16 As[64 * LK];
  __shared__ __bf16 Bs[256 * LK];
  const size_t GS = (size_t)B * D * N;

  int m0 = (blockIdx.x % 98) * 64;
  int e0 = (blockIdx.x / 98) * 256;
  int t = threadIdx.x;
  int lane = t & 63, wave = t >> 6;
  int quad = lane >> 4, l16 = lane & 15;
  int wrow = (wave & 1) * 32;
  int wcol = (wave >> 1) * 128;

  f32x4 acc[16];
  #pragma unroll
  for (int i = 0; i < 16; ++i) acc[i] = (f32x4){0.f, 0.f, 0.f, 0.f};

  const uint4* wsrc = (const uint4*)Wob;
  #pragma unroll 1
  for (int c = 0; c < 24; ++c) {
    int k0 = c * 32;
    __syncthreads();
    #pragma unroll
    for (int i = 0; i < 8; ++i) {
      int idx = t + i * 256;
      int ml = idx & 63, kl = idx >> 6;
      int m = m0 + ml;
      int bb = m / N, n = m % N;
      size_t off = ((size_t)bb * D + k0 + kl) * N + n;
      float v = (float)mixp[off] + (float)mixp[off + GS] +
                (float)mixp[off + 2 * GS] + (float)mixp[off + 3 * GS];
      As[ml * LK + kl] = (__bf16)v;
    }
    for (int p = t; p < 1024; p += 256) {
      int r = p >> 2, sub = p & 3;
      uint4 v = wsrc[(((size_t)(e0 + r)) * D + k0) / 8 + sub];
      *(uint4*)&Bs[r * LK + sub * 8] = v;
    }
    __syncthreads();
    bf16x8 a0 = *(const bf16x8*)&As[(wrow + l16) * LK + quad * 8];
    bf16x8 a1 = *(const bf16x8*)&As[(wrow + 16 + l16) * LK + quad * 8];
    #pragma unroll
    for (int ct = 0; ct < 8; ++ct) {
      bf16x8 bfr = *(const bf16x8*)&Bs[(wcol + ct * 16 + l16) * LK + quad * 8];
      acc[ct]     = __builtin_amdgcn_mfma_f32_16x16x32_bf16(a0, bfr, acc[ct], 0, 0, 0);
      acc[8 + ct] = __builtin_amdgcn_mfma_f32_16x16x32_bf16(a1, bfr, acc[8 + ct], 0, 0, 0);
    }
  }

  #pragma unroll
  for (int ct = 0; ct < 8; ++ct) {
    int e = e0 + wcol + ct * 16 + l16;
    float bov = bo[e];
    #pragma unroll
    for (int rt = 0; rt < 2; ++rt) {
      #pragma unroll
      for (int r = 0; r < 4; ++r) {
        int m = m0 + wrow + rt * 16 + quad * 4 + r;
        out[(size_t)m * D + e] = acc[rt * 8 + ct][r] + bov;
      }
    }
  }
}

// ---------------------------------------------------------------------------
extern "C" void kernel_launch(void* const* d_in, const int* in_sizes, int n_in,
                              void* d_out, int out_size, void* d_ws, size_t ws_size,
                              hipStream_t stream) {
  const float* x  = (const float*)d_in[0];
  const float* Wr = (const float*)d_in[1];
  const float* W1 = (const float*)d_in[2];
  const float* b1 = (const float*)d_in[3];
  const float* W2 = (const float*)d_in[4];
  const float* b2 = (const float*)d_in[5];
  const float* Wo = (const float*)d_in[6];
  const float* bo = (const float*)d_in[7];
  float* out = (float*)d_out;

  char* p = (char*)d_ws;
  auto alloc = [&](size_t bytes) {
    char* r = p;
    p += (bytes + 255) & ~(size_t)255;
    return r;
  };
  __bf16* zb   = (__bf16*)alloc((size_t)B * D * NP * 2);
  float*  mu   = (float*)alloc((size_t)B * D * 4);
  __bf16* W1t  = (__bf16*)alloc((size_t)E * EXB);
  __bf16* W2t  = (__bf16*)alloc((size_t)E * EXB);
  __bf16* Wob  = (__bf16*)alloc((size_t)D * D * 2);
  __bf16* mixp = (__bf16*)alloc((size_t)NGRP * B * D * N * 2);
  float*  probs= (float*)alloc((size_t)B * E * 4);
  int*    idxg = (int*)alloc((size_t)B * TK * 4);
  float*  wg   = (float*)alloc((size_t)B * TK * 4);

  k_ln<<<dim3((B * D) / 256), dim3(256), 0, stream>>>(x, zb, mu);
  k_convert_t<<<dim3(7, E, 2), dim3(256), 0, stream>>>(W1, W2, W1t, W2t);
  k_convert_wo<<<dim3(576), dim3(256), 0, stream>>>(Wo, Wob);
  k_router<<<dim3(B), dim3(256), 0, stream>>>(mu, Wr, probs, idxg, wg);
  k_aux<<<dim3(1), dim3(256), 0, stream>>>(probs, idxg, out + (size_t)B * N * D);
  k_expert<<<dim3(768), dim3(512), 0, stream>>>(zb, W1t, W2t, b1, b2,
                                                idxg, wg, mixp);
  k_outproj<<<dim3(294), dim3(256), 0, stream>>>(mixp, Wob, bo, out);
}

// Round 4
// 471.791 us; speedup vs baseline: 1.6399x; 1.6399x over previous
//
#include <hip/hip_runtime.h>
#include <math.h>

// ---- problem constants ----
constexpr int B  = 32;
constexpr int N  = 196;   // tokens
constexpr int D  = 768;   // channels
constexpr int E  = 200;   // experts
constexpr int TK = 20;    // top-k
constexpr int H  = 196;   // hidden

constexpr int NP = 224;   // padded K-dim (196 -> 7*32)
constexpr int LK = 40;    // LDS stride for k_outproj tiles

constexpr int NGRP = 4;   // expert groups (5 experts each)
// W tile format: per expert: 7 chunks x [k4 0..3][row 0..223] x 16B slots
constexpr int CHB = 14336;     // chunk bytes
constexpr int EXB = 100352;    // expert bytes (per matrix)

typedef __bf16 bf16x8 __attribute__((ext_vector_type(8)));
typedef __bf16 bf16x4 __attribute__((ext_vector_type(4)));
typedef float  f32x4  __attribute__((ext_vector_type(4)));

#define GLDS16(gp, lp)                                                        \
  __builtin_amdgcn_global_load_lds(                                           \
      (const __attribute__((address_space(1))) void*)(gp),                    \
      (__attribute__((address_space(3))) void*)(lp), 16, 0, 0)

// s_waitcnt immediates (gfx9: vm[3:0]|exp[6:4]|lgkm[11:8]|vm[15:14])
#define WAITVM4   __builtin_amdgcn_s_waitcnt(0x0F74)  // vmcnt<=4
#define WAITLGKM0 __builtin_amdgcn_s_waitcnt(0xC07F)  // lgkmcnt==0
#define BAR       __builtin_amdgcn_s_barrier()

// fast tanh-gelu: x * sigmoid(1.595769*(x + 0.044715 x^3)); exp2 form.
__device__ __forceinline__ float gelu_fast(float x) {
  float u = x * fmaf(x * x, 0.044715f, 1.0f);
  float e = exp2f(-2.3022084f * u);
  return x * __builtin_amdgcn_rcpf(1.0f + e);
}

// ---------------------------------------------------------------------------
// Kernel 1: token-mean + LN over N. Block=(b, 64-d tile); transposed write
// staged through LDS so the global write is flat/coalesced.
// ---------------------------------------------------------------------------
__global__ __launch_bounds__(256) void k_ln(const float* __restrict__ x,
                                            __bf16* __restrict__ zb,
                                            float* __restrict__ mu) {
  int b = blockIdx.x / 12, dt = blockIdx.x % 12;
  int d0 = dt * 64;
  int t = threadIdx.x;
  int q = t >> 6, d = t & 63;
  __shared__ float ps[256], pq[256];
  __shared__ float ms[64], rss[64];
  __shared__ alignas(16) __bf16 zt[64 * 224];

  const float* xp = x + ((size_t)b * N + q * 49) * D + d0 + d;
  float s = 0.f, sq = 0.f;
  #pragma unroll 7
  for (int n = 0; n < 49; ++n) {
    float v = xp[(size_t)n * D];
    s += v; sq += v * v;
  }
  ps[t] = s; pq[t] = sq;
  __syncthreads();
  if (t < 64) {
    float S = ps[t] + ps[t + 64] + ps[t + 128] + ps[t + 192];
    float Q = pq[t] + pq[t + 64] + pq[t + 128] + pq[t + 192];
    float m = S * (1.0f / N);
    float var = Q * (1.0f / N) - m * m;
    ms[t] = m; rss[t] = rsqrtf(var + 1e-5f);
    mu[(size_t)b * D + d0 + t] = m;
  }
  __syncthreads();
  float m = ms[d], r = rss[d];
  #pragma unroll 7
  for (int n = 0; n < 49; ++n) {
    float v = xp[(size_t)n * D];
    zt[d * 224 + q * 49 + n] = (__bf16)((v - m) * r);
  }
  for (int i = t; i < 64 * 28; i += 256) {
    int dd = i / 28, cc = 196 + i % 28;
    zt[dd * 224 + cc] = (__bf16)0.f;
  }
  __syncthreads();
  uint4* dst = (uint4*)(zb + ((size_t)b * D + d0) * NP);
  const uint4* srcl = (const uint4*)zt;
  #pragma unroll
  for (int i = 0; i < 7; ++i) dst[i * 256 + t] = srcl[i * 256 + t];
}

// ---------------------------------------------------------------------------
// Kernel 2a: W1,W2 -> tiled bf16 staging format via LDS transpose.
// grid (2 halves of 112 rows, E, 2 matrices). Coalesced reads AND writes.
// ---------------------------------------------------------------------------
__global__ __launch_bounds__(256) void k_convert_t(
    const float* __restrict__ W1, const float* __restrict__ W2,
    __bf16* __restrict__ W1t, __bf16* __restrict__ W2t) {
  int half = blockIdx.x, e = blockIdx.y;
  int r0 = half * 112;
  int nrows = half ? 84 : 112;   // data rows in this half (rows >=196 are pad)
  const float* src = (blockIdx.z ? W2 : W1) + ((size_t)e * 196 + r0) * 196;
  __bf16* dst = (blockIdx.z ? W2t : W1t) + (size_t)e * (EXB / 2);
  __shared__ alignas(16) __bf16 ls[112 * 224];
  int t = threadIdx.x;

  uint4 z4 = {0, 0, 0, 0};
  for (int i = t; i < 3136; i += 256) ((uint4*)ls)[i] = z4;
  __syncthreads();
  int ntot = nrows * 49;         // float4 count
  for (int i = t; i < ntot; i += 256) {
    float4 v = ((const float4*)src)[i];
    int base = i * 4;
    #pragma unroll
    for (int j = 0; j < 4; ++j) {
      int fb = base + j;
      int rr = fb / 196, cc = fb - rr * 196;
      ls[rr * 224 + cc] = (__bf16)((&v.x)[j]);
    }
  }
  __syncthreads();
  for (int i = t; i < 3136; i += 256) {
    int c = i / 448, rem = i - c * 448;
    int k4 = rem / 112, row = rem - k4 * 112;
    uint4 v = *(const uint4*)&ls[row * 224 + c * 32 + k4 * 8];
    *(uint4*)&dst[(size_t)c * 7168 + k4 * 1792 + (r0 + row) * 8] = v;
  }
}

// Kernel 2b: Wo -> bf16
__global__ void k_convert_wo(const float* __restrict__ Wo, __bf16* __restrict__ Wob) {
  int t = blockIdx.x * 256 + threadIdx.x;
  float4 v = *(const float4*)&Wo[t * 4];
  bf16x4 o = {(__bf16)v.x, (__bf16)v.y, (__bf16)v.z, (__bf16)v.w};
  *(bf16x4*)&Wob[t * 4] = o;
}

// ---------------------------------------------------------------------------
// Kernel 3: router — logits (float4), softmax, top-20, renormalized weights.
// ---------------------------------------------------------------------------
__global__ void k_router(const float* __restrict__ mu, const float* __restrict__ Wr,
                         float* __restrict__ probs, int* __restrict__ idxg,
                         float* __restrict__ wg) {
  int b = blockIdx.x;
  int t = threadIdx.x;
  __shared__ float smu[768];
  __shared__ float sp[E];
  __shared__ float smax, ssum;
  __shared__ float svals[TK];
  __shared__ int   sidx[TK];

  for (int i = t; i < 768; i += 256) smu[i] = mu[(size_t)b * D + i];
  __syncthreads();

  float logit = 0.f;
  if (t < E) {
    const float4* wr4 = (const float4*)(Wr + (size_t)t * D);
    const float4* m4  = (const float4*)smu;
    float acc = 0.f;
    #pragma unroll 4
    for (int i = 0; i < 192; ++i) {
      float4 w = wr4[i], m = m4[i];
      acc = fmaf(w.x, m.x, acc); acc = fmaf(w.y, m.y, acc);
      acc = fmaf(w.z, m.z, acc); acc = fmaf(w.w, m.w, acc);
    }
    logit = acc;
    sp[t] = acc;
  }
  __syncthreads();
  if (t == 0) {
    float mx = sp[0];
    for (int e = 1; e < E; ++e) mx = fmaxf(mx, sp[e]);
    smax = mx;
  }
  __syncthreads();
  if (t < E) sp[t] = expf(logit - smax);
  __syncthreads();
  if (t == 0) {
    float s = 0.f;
    for (int e = 0; e < E; ++e) s += sp[e];
    ssum = s;
  }
  __syncthreads();
  if (t < E) {
    sp[t] = sp[t] / ssum;
    probs[(size_t)b * E + t] = sp[t];
  }
  __syncthreads();

  for (int k = 0; k < TK; ++k) {
    if (t < 64) {
      float bv = -1e30f; int bi = 0;
      for (int e = t; e < E; e += 64) {
        float v = sp[e];
        if (v > bv) { bv = v; bi = e; }
      }
      #pragma unroll
      for (int off = 32; off > 0; off >>= 1) {
        float ov = __shfl_down(bv, off);
        int   oi = __shfl_down(bi, off);
        if (ov > bv || (ov == bv && oi < bi)) { bv = ov; bi = oi; }
      }
      if (t == 0) {
        svals[k] = bv; sidx[k] = bi;
        sp[bi] = -2e30f;
      }
    }
    __syncthreads();
  }
  if (t == 0) {
    float s = 0.f;
    for (int k = 0; k < TK; ++k) s += svals[k];
    float inv = 1.0f / s;
    for (int k = 0; k < TK; ++k) {
      wg[b * TK + k]   = svals[k] * inv;
      idxg[b * TK + k] = sidx[k];
    }
  }
}

// ---------------------------------------------------------------------------
// Kernel 4: aux loss -> out[B*N*D]
// ---------------------------------------------------------------------------
__global__ void k_aux(const float* __restrict__ probs, const int* __restrict__ idxg,
                      float* __restrict__ out_aux) {
  __shared__ float cs[E];
  int t = threadIdx.x;
  if (t < E) {
    float s = 0.f;
    for (int b = 0; b < B; ++b) s += probs[(size_t)b * E + t];
    cs[t] = s;
  }
  __syncthreads();
  if (t == 0) {
    float a = 0.f;
    for (int b = 0; b < B; ++b) a += cs[idxg[b * TK]];
    out_aux[0] = a * ((float)E / ((float)B * (float)B));
  }
}

// ---------------------------------------------------------------------------
// Kernel 5: fused expert MLP. 512 thr, 128-row d-tile, 1 block/CU.
// 3-deep async chunk pipeline (issue c+3 while computing c) — ~2 iters of
// latency cover. Epilogue transposes mix through the freed `at` buffer so the
// global write is (g,b,n,d) coalesced. grid 768 = 3 exact rounds, XCD-swizzled.
// ---------------------------------------------------------------------------
__global__ __launch_bounds__(512, 1) void k_expert(
    const __bf16* __restrict__ zb, const __bf16* __restrict__ W1t,
    const __bf16* __restrict__ W2t, const float* __restrict__ b1,
    const float* __restrict__ b2, const int* __restrict__ idxg,
    const float* __restrict__ wg, __bf16* __restrict__ mixg) {
  __shared__ alignas(16) __bf16 zs[28672];        // [k8 0..27][row 0..127] x 8
  __shared__ alignas(16) __bf16 atu[29568];       // at: 28672 | at2: 224x132
  __shared__ alignas(16) __bf16 ws[3 * 7168];     // 3 chunk buffers
  __shared__ __bf16 b1s[5 * 196];
  __shared__ __bf16 b2s[5 * 196];
  __shared__ int   eidx_s[8];
  __shared__ float w_s[8];

  int x = blockIdx.x & 7, rr_ = blockIdx.x >> 3;
  int j = rr_ / 6, dt = rr_ - j * 6;
  int gid = j * 8 + x;
  int g = gid & 3, b = gid >> 2;
  int d0 = dt * 128;

  int t = threadIdx.x;
  int lane = t & 63, wave = t >> 6;
  int quad = lane >> 4, l16 = lane & 15;
  int wrow = (wave & 3) * 32;
  int wcol = (wave >> 2) * 112;

  // ---- prologue: expert ids/weights + biases into LDS ----
  if (t < 5) {
    eidx_s[t] = idxg[b * TK + g * 5 + t];
    w_s[t]    = wg[b * TK + g * 5 + t];
  }
  for (int i = t; i < 980; i += 512) {
    int kk = i / 196, col = i - kk * 196;
    int ee = idxg[b * TK + g * 5 + kk];
    b1s[i] = (__bf16)b1[ee * 196 + col];
    b2s[i] = (__bf16)b2[ee * 196 + col];
  }
  __syncthreads();   // drains prologue vmem; nothing else outstanding

  // ---- z tile staging (7 GLDS per thread-slot group) ----
  {
    const char* zbase = (const char*)zb + (size_t)(b * D + d0) * (NP * 2);
    #pragma unroll
    for (int p = 0; p < 7; ++p) {
      int s = p * 512 + t;
      GLDS16(zbase + (s & 127) * (NP * 2) + (s >> 7) * 16, &zs[s * 8]);
    }
  }

  // ---- W staging offsets ----
  int soff0 = t * 16;
  int soff1 = (t < 384) ? (512 + t) * 16 : (t - 384) * 16;

  auto issue = [&](int qn) {
    int qs = qn > 69 ? 69 : qn;
    int kq = qs / 14;
    int rem = qs - kq * 14;
    int ee = eidx_s[kq];
    const char* src;
    if (rem < 7) src = (const char*)W1t + (size_t)ee * EXB + rem * CHB;
    else         src = (const char*)W2t + (size_t)ee * EXB + (rem - 7) * CHB;
    char* lb = (char*)ws + (qn % 3) * CHB;
    GLDS16(src + soff0, lb + soff0);
    GLDS16(src + soff1, lb + soff1);
  };
  issue(0); issue(1); issue(2);

  f32x4 macc[14];
  #pragma unroll
  for (int i = 0; i < 14; ++i) macc[i] = (f32x4){0.f, 0.f, 0.f, 0.f};

  int qn = 3;
  #pragma unroll 1
  for (int kk = 0; kk < 5; ++kk) {
    float wkv = w_s[kk];

    // ---- GEMM1: h = z @ W1^T ----
    f32x4 hacc[14];
    #pragma unroll
    for (int i = 0; i < 14; ++i) hacc[i] = (f32x4){0.f, 0.f, 0.f, 0.f};

    #pragma unroll 1
    for (int c = 0; c < 7; ++c) {
      int q = kk * 14 + c;
      WAITVM4;
      BAR;
      const __bf16* bp = ws + (q % 3) * 7168;
      bf16x8 a0 = *(const bf16x8*)&zs[(c * 4 + quad) * 1024 + (wrow + l16) * 8];
      bf16x8 a1 = *(const bf16x8*)&zs[(c * 4 + quad) * 1024 + (wrow + 16 + l16) * 8];
      #pragma unroll
      for (int ct = 0; ct < 7; ++ct) {
        bf16x8 bf = *(const bf16x8*)&bp[(quad * 224 + wcol + ct * 16 + l16) * 8];
        hacc[ct]     = __builtin_amdgcn_mfma_f32_16x16x32_bf16(a0, bf, hacc[ct], 0, 0, 0);
        hacc[7 + ct] = __builtin_amdgcn_mfma_f32_16x16x32_bf16(a1, bf, hacc[7 + ct], 0, 0, 0);
      }
      BAR;
      issue(qn); ++qn;
    }

    // ---- epilogue: a = gelu(h+b1)*w_k -> at ; macc += w_k*b2 ----
    #pragma unroll
    for (int ct = 0; ct < 7; ++ct) {
      int hcol = wcol + ct * 16 + l16;
      bool valid = hcol < 196;
      float bv  = valid ? (float)b1s[kk * 196 + hcol] : 0.f;
      float b2v = valid ? (float)b2s[kk * 196 + hcol] * wkv : 0.f;
      #pragma unroll
      for (int rt = 0; rt < 2; ++rt) {
        f32x4 hv = hacc[rt * 7 + ct];
        #pragma unroll
        for (int rx = 0; rx < 4; ++rx) {
          int row = wrow + rt * 16 + quad * 4 + rx;
          float gv = gelu_fast(hv[rx] + bv) * wkv;
          atu[((hcol >> 3) * 128 + row) * 8 + (hcol & 7)] = (__bf16)gv;
          macc[rt * 7 + ct][rx] += b2v;
        }
      }
    }
    WAITLGKM0;   // at-writes drained before the barrier in first GEMM2 chunk

    // ---- GEMM2: mix += a @ W2^T ----
    #pragma unroll 1
    for (int c = 0; c < 7; ++c) {
      int q = kk * 14 + 7 + c;
      WAITVM4;
      BAR;
      const __bf16* bp = ws + (q % 3) * 7168;
      bf16x8 a0 = *(const bf16x8*)&atu[(c * 4 + quad) * 1024 + (wrow + l16) * 8];
      bf16x8 a1 = *(const bf16x8*)&atu[(c * 4 + quad) * 1024 + (wrow + 16 + l16) * 8];
      #pragma unroll
      for (int ct = 0; ct < 7; ++ct) {
        bf16x8 bf = *(const bf16x8*)&bp[(quad * 224 + wcol + ct * 16 + l16) * 8];
        macc[ct]     = __builtin_amdgcn_mfma_f32_16x16x32_bf16(a0, bf, macc[ct], 0, 0, 0);
        macc[7 + ct] = __builtin_amdgcn_mfma_f32_16x16x32_bf16(a1, bf, macc[7 + ct], 0, 0, 0);
      }
      BAR;
      issue(qn); ++qn;
    }
  }

  // ---- transpose mix through atu ([n][d], stride 132), then coalesced write ----
  // (final BAR above guarantees all waves are done reading atu)
  #pragma unroll
  for (int ct = 0; ct < 7; ++ct) {
    int ncol = wcol + ct * 16 + l16;
    #pragma unroll
    for (int rt = 0; rt < 2; ++rt) {
      #pragma unroll
      for (int rx = 0; rx < 4; ++rx) {
        int dr = wrow + rt * 16 + quad * 4 + rx;
        atu[ncol * 132 + dr] = (__bf16)macc[rt * 7 + ct][rx];
      }
    }
  }
  __syncthreads();
  __bf16* mp = mixg + ((size_t)(g * B + b) * N) * D + d0;
  #pragma unroll
  for (int i = 0; i < 7; ++i) {
    int s = i * 512 + t;
    if (s < 3136) {
      int n = s >> 4, c = s & 15;
      const uint2* pa = (const uint2*)&atu[n * 132 + c * 8];
      uint2 v0 = pa[0], v1 = pa[1];
      uint4 v = {v0.x, v0.y, v1.x, v1.y};
      *(uint4*)&mp[(size_t)n * D + c * 8] = v;
    }
  }
}

// ---------------------------------------------------------------------------
// Kernel 6: out = (sum_g mixg_g) @ Wo^T + bo.  mixg is (g, m, d) flat with
// m = b*196+n, so the A-tile is a plain row-major k-contiguous load.
// ---------------------------------------------------------------------------
__global__ __launch_bounds__(256, 2) void k_outproj(
    const __bf16* __restrict__ mixg, const __bf16* __restrict__ Wob,
    const float* __restrict__ bo, float* __restrict__ out) {
  __shared__ alignas(16) __bf16 As[64 * LK];
  __shared__ alignas(16) __bf16 Bs[256 * LK];
  const size_t GS = (size_t)B * N * D;

  int m0 = (blockIdx.x % 98) * 64;
  int e0 = (blockIdx.x / 98) * 256;
  int t = threadIdx.x;
  int lane = t & 63, wave = t >> 6;
  int quad = lane >> 4, l16 = lane & 15;
  int wrow = (wave & 1) * 32;
  int wcol = (wave >> 1) * 128;
  int arow = t >> 2, ach = t & 3;
  const __bf16* ap0 = mixg + (size_t)(m0 + arow) * D + ach * 8;

  f32x4 acc[16];
  #pragma unroll
  for (int i = 0; i < 16; ++i) acc[i] = (f32x4){0.f, 0.f, 0.f, 0.f};

  const uint4* wsrc = (const uint4*)Wob;
  #pragma unroll 1
  for (int c = 0; c < 24; ++c) {
    int k0 = c * 32;
    __syncthreads();
    {
      const __bf16* ap = ap0 + k0;
      bf16x8 g0 = *(const bf16x8*)(ap);
      bf16x8 g1 = *(const bf16x8*)(ap + GS);
      bf16x8 g2 = *(const bf16x8*)(ap + 2 * GS);
      bf16x8 g3 = *(const bf16x8*)(ap + 3 * GS);
      bf16x8 r;
      #pragma unroll
      for (int jj = 0; jj < 8; ++jj)
        r[jj] = (__bf16)((float)g0[jj] + (float)g1[jj] + (float)g2[jj] + (float)g3[jj]);
      *(bf16x8*)&As[arow * LK + ach * 8] = r;
    }
    for (int p = t; p < 1024; p += 256) {
      int rr = p >> 2, sub = p & 3;
      uint4 v = wsrc[(((size_t)(e0 + rr)) * D + k0) / 8 + sub];
      *(uint4*)&Bs[rr * LK + sub * 8] = v;
    }
    __syncthreads();
    bf16x8 a0 = *(const bf16x8*)&As[(wrow + l16) * LK + quad * 8];
    bf16x8 a1 = *(const bf16x8*)&As[(wrow + 16 + l16) * LK + quad * 8];
    #pragma unroll
    for (int ct = 0; ct < 8; ++ct) {
      bf16x8 bfr = *(const bf16x8*)&Bs[(wcol + ct * 16 + l16) * LK + quad * 8];
      acc[ct]     = __builtin_amdgcn_mfma_f32_16x16x32_bf16(a0, bfr, acc[ct], 0, 0, 0);
      acc[8 + ct] = __builtin_amdgcn_mfma_f32_16x16x32_bf16(a1, bfr, acc[8 + ct], 0, 0, 0);
    }
  }

  #pragma unroll
  for (int ct = 0; ct < 8; ++ct) {
    int e = e0 + wcol + ct * 16 + l16;
    float bov = bo[e];
    #pragma unroll
    for (int rt = 0; rt < 2; ++rt) {
      #pragma unroll
      for (int rx = 0; rx < 4; ++rx) {
        int m = m0 + wrow + rt * 16 + quad * 4 + rx;
        out[(size_t)m * D + e] = acc[rt * 8 + ct][rx] + bov;
      }
    }
  }
}

// ---------------------------------------------------------------------------
extern "C" void kernel_launch(void* const* d_in, const int* in_sizes, int n_in,
                              void* d_out, int out_size, void* d_ws, size_t ws_size,
                              hipStream_t stream) {
  const float* x  = (const float*)d_in[0];
  const float* Wr = (const float*)d_in[1];
  const float* W1 = (const float*)d_in[2];
  const float* b1 = (const float*)d_in[3];
  const float* W2 = (const float*)d_in[4];
  const float* b2 = (const float*)d_in[5];
  const float* Wo = (const float*)d_in[6];
  const float* bo = (const float*)d_in[7];
  float* out = (float*)d_out;

  char* p = (char*)d_ws;
  auto alloc = [&](size_t bytes) {
    char* r = p;
    p += (bytes + 255) & ~(size_t)255;
    return r;
  };
  __bf16* zb   = (__bf16*)alloc((size_t)B * D * NP * 2);
  float*  mu   = (float*)alloc((size_t)B * D * 4);
  __bf16* W1t  = (__bf16*)alloc((size_t)E * EXB);
  __bf16* W2t  = (__bf16*)alloc((size_t)E * EXB);
  __bf16* Wob  = (__bf16*)alloc((size_t)D * D * 2);
  __bf16* mixg = (__bf16*)alloc((size_t)NGRP * B * N * D * 2);
  float*  probs= (float*)alloc((size_t)B * E * 4);
  int*    idxg = (int*)alloc((size_t)B * TK * 4);
  float*  wg   = (float*)alloc((size_t)B * TK * 4);

  k_ln<<<dim3(B * 12), dim3(256), 0, stream>>>(x, zb, mu);
  k_convert_t<<<dim3(2, E, 2), dim3(256), 0, stream>>>(W1, W2, W1t, W2t);
  k_convert_wo<<<dim3(576), dim3(256), 0, stream>>>(Wo, Wob);
  k_router<<<dim3(B), dim3(256), 0, stream>>>(mu, Wr, probs, idxg, wg);
  k_aux<<<dim3(1), dim3(256), 0, stream>>>(probs, idxg, out + (size_t)B * N * D);
  k_expert<<<dim3(768), dim3(512), 0, stream>>>(zb, W1t, W2t, b1, b2,
                                                idxg, wg, mixg);
  k_outproj<<<dim3(294), dim3(256), 0, stream>>>(mixg, Wob, bo, out);
}